// Round 1
// baseline (1073.611 us; speedup 1.0000x reference)
//
#include <hip/hip_runtime.h>

typedef unsigned short u16;
typedef __attribute__((ext_vector_type(8))) short short8v;
typedef __attribute__((ext_vector_type(4))) float f32x4;

#define GLD_LDS(g, l) __builtin_amdgcn_global_load_lds( \
    (const __attribute__((address_space(1))) void*)(g), \
    (__attribute__((address_space(3))) void*)(l), 16, 0, 0)

__device__ __forceinline__ u16 f2bf(float f){
  union { float f; unsigned u; } v; v.f = f;
  unsigned r = v.u + 0x7FFFu + ((v.u >> 16) & 1u);
  return (u16)(r >> 16);
}
__device__ __forceinline__ float bf2f(u16 h){
  union { unsigned u; float f; } v; v.u = ((unsigned)h) << 16;
  return v.f;
}

// ---------------------------------------------------------------------------
// convert decoder weights to bf16 (no transpose needed: B-frag reads rows of
// w[g][k], k-contiguous)
__global__ void wcvt_kernel(const float* w_ih, const float* w_hh, u16* wihB, u16* whhB){
  int i = blockIdx.x*256 + threadIdx.x;
  if (i < 288*96){ wihB[i] = f2bf(w_ih[i]); whhB[i] = f2bf(w_hh[i]); }
}

// ---------------------------------------------------------------------------
// K = memory_past@Wk^T + bk  -> Kb bf16 [32768][64], col-swizzled (k ^ 8*(key&7)), zero-padded k=48..63
// V = memory_fut @Wv^T + bv  -> Vc bf16 [128 chunks][48][256], key-swizzled (kic ^ 8*(d&7))
__global__ __launch_bounds__(256) void kv_kernel(
    const float* mp, const float* mf, const float* Wk, const float* bk,
    const float* Wv, const float* bv, u16* Kb, u16* Vc)
{
  __shared__ float sWk[48*49], sWv[48*49];
  __shared__ float sMp[32*49], sMf[32*49];
  int tid = threadIdx.x;
  int r0 = blockIdx.x * 32;
  for (int i = tid; i < 48*48; i += 256){ int d = i/48, k = i%48; sWk[d*49+k] = Wk[i]; sWv[d*49+k] = Wv[i]; }
  for (int i = tid; i < 32*48; i += 256){ int r = i/48, k = i%48; sMp[r*49+k] = mp[r0*48 + i]; sMf[r*49+k] = mf[r0*48 + i]; }
  __syncthreads();
  // K outputs, row-major mapping
  for (int o = tid; o < 32*48; o += 256){
    int r = o/48, d = o%48;
    float a = bk[d];
    #pragma unroll
    for (int k = 0; k < 48; ++k) a += sMp[r*49+k]*sWk[d*49+k];
    int key = r0 + r; int sw = 8*(key&7);
    Kb[key*64 + (d ^ sw)] = f2bf(a);
  }
  // K zero pad slots
  for (int o = tid; o < 32*16; o += 256){
    int r = o/16, d = 48 + (o%16);
    int key = r0 + r; int sw = 8*(key&7);
    Kb[key*64 + (d ^ sw)] = 0;
  }
  // V outputs, dim-major mapping (coalesced transposed writes)
  for (int o = tid; o < 48*32; o += 256){
    int d = o/32, r = o%32;
    float a = bv[d];
    #pragma unroll
    for (int k = 0; k < 48; ++k) a += sMf[r*49+k]*sWv[d*49+k];
    int key = r0 + r; int ch = key >> 8; int kic = key & 255;
    Vc[(ch*48 + d)*256 + (kic ^ (8*(d&7)))] = f2bf(a);
  }
}

// ---------------------------------------------------------------------------
// encoder: conv1d(2->48,3,pad1)+ReLU then 8-step GRU(48); also q0 = h@Wq^T+bq
__global__ __launch_bounds__(256) void enc_kernel(
    const float* past, const float* conv_w, const float* conv_b,
    const float* w_ih, const float* w_hh, const float* b_ih, const float* b_hh,
    const float* Wq, const float* bq, float* stateP, float* qb)
{
  __shared__ float sWih[144*49];
  __shared__ float sWhh[144*49];
  __shared__ float sPast[8*16];
  __shared__ float sEmb[8*48];
  __shared__ float sGi[8*144];
  __shared__ float sGh[8*144];
  __shared__ float sH[8*48];
  __shared__ float sCw[288];
  int tid = threadIdx.x;
  int r0 = blockIdx.x * 8;
  for (int i = tid; i < 144*48; i += 256){ int g = i/48, k = i%48; sWih[g*49+k] = w_ih[i]; sWhh[g*49+k] = w_hh[i]; }
  for (int i = tid; i < 128; i += 256) sPast[i] = past[r0*16 + i];
  for (int i = tid; i < 288; i += 256) sCw[i] = conv_w[i];
  for (int i = tid; i < 384; i += 256) sH[i] = 0.f;
  __syncthreads();
  for (int t = 0; t < 8; ++t){
    for (int o = tid; o < 384; o += 256){
      int r = o/48, d = o%48;
      float a = conv_b[d];
      #pragma unroll
      for (int kt = 0; kt < 3; ++kt){
        int tau = t + kt - 1;
        if (tau >= 0 && tau < 8){
          a += sPast[r*16 + tau*2 + 0] * sCw[d*6 + kt];
          a += sPast[r*16 + tau*2 + 1] * sCw[d*6 + 3 + kt];
        }
      }
      sEmb[o] = fmaxf(a, 0.f);
    }
    __syncthreads();
    for (int o = tid; o < 2304; o += 256){
      int mat = o / 1152; int rem = o % 1152; int r = rem/144, g = rem%144;
      const float* src = mat ? (sH + r*48) : (sEmb + r*48);
      const float* w   = mat ? (sWhh + g*49) : (sWih + g*49);
      float a = mat ? b_hh[g] : b_ih[g];
      #pragma unroll
      for (int k = 0; k < 48; ++k) a += src[k]*w[k];
      if (mat) sGh[rem] = a; else sGi[rem] = a;
    }
    __syncthreads();
    for (int o = tid; o < 384; o += 256){
      int r = o/48, d = o%48;
      float rg_ = 1.f/(1.f+__expf(-(sGi[r*144+d]    + sGh[r*144+d])));
      float zz  = 1.f/(1.f+__expf(-(sGi[r*144+48+d] + sGh[r*144+48+d])));
      float nn  = tanhf(sGi[r*144+96+d] + rg_*sGh[r*144+96+d]);
      sH[r*48+d] = (1.f-zz)*nn + zz*sH[r*48+d];
    }
    __syncthreads();
  }
  for (int o = tid; o < 384; o += 256){
    int r = o/48, d = o%48;
    stateP[(r0+r)*48+d] = sH[r*48+d];
    float a = bq[d];
    #pragma unroll
    for (int k = 0; k < 48; ++k) a += sH[r*48+k]*Wq[d*48+k];
    qb[(r0+r)*48+d] = a;
  }
}

// ---------------------------------------------------------------------------
// flash split-K attention partials. grid = 4 rowgroups x 128 chunks (512 blk).
// block = 256 thr (4 waves); wave handles 2x16 q-rows; chunk = 256 keys (4 tiles of 64).
__global__ __launch_bounds__(256) void flash_kernel(
    const float* qb, const u16* Kb, const u16* Vc,
    float* m_part, float* l_part, float* acc_part)
{
  __shared__ __align__(16) u16 sVt[48*256];   // 24KB, transposed V chunk
  __shared__ __align__(16) u16 sK[64*64];     // 8KB, one key tile
  __shared__ __align__(16) u16 sPQ[8*1152];   // 18KB: per-wave P buffers / q staging
  int tid = threadIdx.x;
  int wid = tid >> 6, lane = tid & 63;
  int qd = lane >> 4, ln = lane & 15;
  int bx = blockIdx.x;
  int rg = bx >> 7, ch = bx & 127;
  int rowbase = rg * 128;

  // stage Vt chunk (flat 24KB copy, pre-swizzled in global)
  {
    const char* src = (const char*)(Vc + ch*48*256);
    #pragma unroll
    for (int i = 0; i < 6; ++i){
      int off = wid*6144 + i*1024;
      GLD_LDS(src + off + lane*16, ((char*)(void*)sVt) + off);
    }
  }
  // stage q (fp32 -> bf16, swizzled) into sPQ region
  {
    unsigned* zq = (unsigned*)sPQ;
    for (int i = tid; i < 4096; i += 256) zq[i] = 0;
    __syncthreads();
    for (int i = tid; i < 128*48; i += 256){
      int rl = i/48, k = i%48;
      sPQ[rl*64 + (k ^ (8*(rl&7)))] = f2bf(qb[(rowbase + rl)*48 + k]);
    }
    __syncthreads();
  }
  short8v aq[2][2];
  #pragma unroll
  for (int rt = 0; rt < 2; ++rt){
    int rl = wid*32 + rt*16 + ln;
    #pragma unroll
    for (int kc = 0; kc < 2; ++kc)
      aq[rt][kc] = *(const short8v*)&sPQ[rl*64 + ((kc*32 + qd*8) ^ (8*(rl&7)))];
  }
  __syncthreads();   // q region may now be reused as P buffers

  f32x4 acc[2][3];
  f32x4 zf = {0.f,0.f,0.f,0.f};
  #pragma unroll
  for (int rt=0; rt<2; ++rt){ acc[rt][0]=zf; acc[rt][1]=zf; acc[rt][2]=zf; }
  float mrun[2][4], lrun[2][4];
  #pragma unroll
  for (int rt=0; rt<2; ++rt)
    #pragma unroll
    for (int r=0; r<4; ++r){ mrun[rt][r] = -3.0e38f; lrun[rt][r] = 0.f; }

  u16* sPw[2] = { sPQ + (wid*2+0)*1152, sPQ + (wid*2+1)*1152 };

  for (int kt = 0; kt < 4; ++kt){
    __syncthreads();
    {
      const char* ksrc = (const char*)(Kb + (ch*256 + kt*64)*64);
      #pragma unroll
      for (int i = 0; i < 2; ++i){
        int off = wid*2048 + i*1024;
        GLD_LDS(ksrc + off + lane*16, ((char*)(void*)sK) + off);
      }
    }
    __syncthreads();
    // K B-frags (shared by both rowtiles)
    short8v kb[4][2];
    #pragma unroll
    for (int nt=0; nt<4; ++nt)
      #pragma unroll
      for (int kc=0; kc<2; ++kc){
        int key = nt*16 + ln;
        kb[nt][kc] = *(const short8v*)&sK[key*64 + ((kc*32 + qd*8) ^ (8*(key&7)))];
      }
    #pragma unroll
    for (int rt=0; rt<2; ++rt){
      f32x4 s[4];
      #pragma unroll
      for (int nt=0; nt<4; ++nt){
        f32x4 z = zf;
        z = __builtin_amdgcn_mfma_f32_16x16x32_bf16(aq[rt][0], kb[nt][0], z, 0,0,0);
        z = __builtin_amdgcn_mfma_f32_16x16x32_bf16(aq[rt][1], kb[nt][1], z, 0,0,0);
        s[nt] = z;
      }
      u16* sP = sPw[rt];
      #pragma unroll
      for (int r=0; r<4; ++r){
        float rmax = fmaxf(fmaxf(s[0][r], s[1][r]), fmaxf(s[2][r], s[3][r]));
        #pragma unroll
        for (int msk=1; msk<16; msk<<=1) rmax = fmaxf(rmax, __shfl_xor(rmax, msk));
        float mnew  = fmaxf(mrun[rt][r], rmax);
        float alpha = __expf(mrun[rt][r] - mnew);
        float p0 = __expf(s[0][r]-mnew), p1 = __expf(s[1][r]-mnew);
        float p2 = __expf(s[2][r]-mnew), p3 = __expf(s[3][r]-mnew);
        float rsum = (p0+p1)+(p2+p3);
        #pragma unroll
        for (int msk=1; msk<16; msk<<=1) rsum += __shfl_xor(rsum, msk);
        lrun[rt][r] = lrun[rt][r]*alpha + rsum;
        mrun[rt][r] = mnew;
        acc[rt][0][r] *= alpha; acc[rt][1][r] *= alpha; acc[rt][2][r] *= alpha;
        int row = qd*4 + r;
        sP[row*72 +      ln] = f2bf(p0);
        sP[row*72 + 16 + ln] = f2bf(p1);
        sP[row*72 + 32 + ln] = f2bf(p2);
        sP[row*72 + 48 + ln] = f2bf(p3);
      }
    }
    // V B-frags
    short8v vb[2][3];
    #pragma unroll
    for (int kc=0; kc<2; ++kc)
      #pragma unroll
      for (int dt=0; dt<3; ++dt){
        int dim = dt*16 + ln;
        vb[kc][dt] = *(const short8v*)&sVt[dim*256 + ((kt*64 + kc*32 + qd*8) ^ (8*(dim&7)))];
      }
    #pragma unroll
    for (int rt=0; rt<2; ++rt){
      u16* sP = sPw[rt];
      short8v pa0 = *(const short8v*)&sP[ln*72 +      qd*8];
      short8v pa1 = *(const short8v*)&sP[ln*72 + 32 + qd*8];
      #pragma unroll
      for (int dt=0; dt<3; ++dt){
        acc[rt][dt] = __builtin_amdgcn_mfma_f32_16x16x32_bf16(pa0, vb[0][dt], acc[rt][dt], 0,0,0);
        acc[rt][dt] = __builtin_amdgcn_mfma_f32_16x16x32_bf16(pa1, vb[1][dt], acc[rt][dt], 0,0,0);
      }
    }
  }
  // write partials
  #pragma unroll
  for (int rt=0; rt<2; ++rt){
    int rowt = rowbase + wid*32 + rt*16;
    if (ln == 0){
      #pragma unroll
      for (int r=0; r<4; ++r){
        int row = rowt + qd*4 + r;
        m_part[ch*512 + row] = mrun[rt][r];
        l_part[ch*512 + row] = lrun[rt][r];
      }
    }
    #pragma unroll
    for (int dt=0; dt<3; ++dt)
      #pragma unroll
      for (int r=0; r<4; ++r){
        int row = rowt + qd*4 + r;
        acc_part[(ch*512 + row)*48 + dt*16 + ln] = acc[rt][dt][r];
      }
  }
}

// ---------------------------------------------------------------------------
// combine partials -> att; pred write; c = q+att; q_next = c@Wq^T+bq
__global__ __launch_bounds__(64) void combine_kernel(
    const float* m_part, const float* l_part, const float* acc_part,
    const float* Wq, const float* bq, float* qb, float* pred, int iter)
{
  __shared__ float sM[128], sL[128], sEw[128], sC[48];
  int row = blockIdx.x;
  int tid = threadIdx.x;
  for (int c = tid; c < 128; c += 64){
    sM[c] = m_part[c*512 + row];
    sL[c] = l_part[c*512 + row];
  }
  __syncthreads();
  float mg = -3.0e38f;
  #pragma unroll 8
  for (int c = 0; c < 128; ++c) mg = fmaxf(mg, sM[c]);
  for (int c = tid; c < 128; c += 64) sEw[c] = __expf(sM[c] - mg);
  __syncthreads();
  float lg = 0.f;
  #pragma unroll 8
  for (int c = 0; c < 128; ++c) lg += sEw[c]*sL[c];
  if (tid < 48){
    float att = 0.f;
    #pragma unroll 8
    for (int c = 0; c < 128; ++c) att += sEw[c]*acc_part[(c*512+row)*48 + tid];
    att /= lg;
    pred[(row*20 + iter)*48 + tid] = att;
    sC[tid] = qb[row*48 + tid] + att;
  }
  __syncthreads();
  if (tid < 48){
    float a = bq[tid];
    #pragma unroll
    for (int k = 0; k < 48; ++k) a += sC[k]*Wq[tid*48 + k];
    qb[row*48 + tid] = a;
  }
}

// ---------------------------------------------------------------------------
// decoder GRU step via MFMA. one wave per 16 rows (grid 640).
// STEP0: G1 = info@w_ih^T (+b_ih), other side = b_hh, h_old = 0.
// else : G1 = h@w_hh^T (+b_hh), other side = b_ih.
template<bool STEP0>
__global__ __launch_bounds__(64) void dec_kernel(
    const u16* wB, const float* b_own, const float* b_oth,
    const float* stateP, const float* pred, const float* obs,
    const u16* h_in, u16* h_out, float* pres,
    const float* fc_w, const float* fc_b, float* out, int t)
{
  __shared__ __align__(16) u16 sX[16*96];
  int lane = threadIdx.x;
  int qd = lane >> 4, ln = lane & 15;
  int r0 = blockIdx.x * 16;
  if (STEP0){
    for (int i = lane; i < 16*96; i += 64){
      int r = i/96, k = i%96;
      int row = r0 + r;
      float v = (k < 48) ? stateP[(row/20)*48 + k] : pred[row*48 + (k-48)];
      sX[i] = f2bf(v);
    }
  } else {
    const unsigned* src = (const unsigned*)(h_in + r0*96);
    for (int i = lane; i < 768; i += 64) ((unsigned*)sX)[i] = src[i];
  }
  __syncthreads();
  short8v xa[3];
  #pragma unroll
  for (int kc = 0; kc < 3; ++kc) xa[kc] = *(const short8v*)&sX[ln*96 + kc*32 + qd*8];
  f32x4 acc[18];
  f32x4 zf = {0.f,0.f,0.f,0.f};
  #pragma unroll
  for (int i = 0; i < 18; ++i) acc[i] = zf;
  #pragma unroll
  for (int nt = 0; nt < 18; ++nt){
    #pragma unroll
    for (int kc = 0; kc < 3; ++kc){
      short8v wb = *(const short8v*)&wB[(nt*16 + ln)*96 + kc*32 + qd*8];
      acc[nt] = __builtin_amdgcn_mfma_f32_16x16x32_bf16(xa[kc], wb, acc[nt], 0,0,0);
    }
  }
  float px[4] = {0,0,0,0}, py[4] = {0,0,0,0};
  #pragma unroll
  for (int r = 0; r < 4; ++r){
    int row = r0 + qd*4 + r;
    #pragma unroll
    for (int i = 0; i < 6; ++i){
      int d = i*16 + ln;
      float g1r = acc[i][r]    + b_own[d];
      float g1z = acc[i+6][r]  + b_own[96+d];
      float g1n = acc[i+12][r] + b_own[192+d];
      float rr = 1.f/(1.f+__expf(-(g1r + b_oth[d])));
      float zz = 1.f/(1.f+__expf(-(g1z + b_oth[96+d])));
      float inn, hn;
      if (STEP0){ inn = g1n; hn = b_oth[192+d]; }
      else      { inn = b_oth[192+d]; hn = g1n; }
      float nn = tanhf(inn + rr*hn);
      float hold = STEP0 ? 0.f : bf2f(sX[(qd*4+r)*96 + d]);
      float hv = (1.f-zz)*nn + zz*hold;
      h_out[row*96 + d] = f2bf(hv);
      px[r] += fc_w[d]*hv;
      py[r] += fc_w[96+d]*hv;
    }
  }
  #pragma unroll
  for (int msk = 8; msk >= 1; msk >>= 1){
    #pragma unroll
    for (int r = 0; r < 4; ++r){
      px[r] += __shfl_xor(px[r], msk);
      py[r] += __shfl_xor(py[r], msk);
    }
  }
  if (ln == 0){
    #pragma unroll
    for (int r = 0; r < 4; ++r){
      int row = r0 + qd*4 + r;
      float p0, p1;
      if (STEP0){ p0 = obs[(row/20)*16+14]; p1 = obs[(row/20)*16+15]; }
      else      { p0 = pres[row*2]; p1 = pres[row*2+1]; }
      p0 += px[r] + fc_b[0];
      p1 += py[r] + fc_b[1];
      pres[row*2] = p0; pres[row*2+1] = p1;
      out[(row*12+t)*2+0] = p0;
      out[(row*12+t)*2+1] = p1;
    }
  }
}

// ---------------------------------------------------------------------------
extern "C" void kernel_launch(void* const* d_in, const int* in_sizes, int n_in,
                              void* d_out, int out_size, void* d_ws, size_t ws_size,
                              hipStream_t stream)
{
  const float* past        = (const float*)d_in[0];
  const float* obs         = (const float*)d_in[1];
  const float* conv_w      = (const float*)d_in[2];
  const float* conv_b      = (const float*)d_in[3];
  const float* enc_w_ih    = (const float*)d_in[4];
  const float* enc_w_hh    = (const float*)d_in[5];
  const float* enc_b_ih    = (const float*)d_in[6];
  const float* enc_b_hh    = (const float*)d_in[7];
  const float* memory_past = (const float*)d_in[8];
  const float* memory_fut  = (const float*)d_in[9];
  const float* Wq = (const float*)d_in[10];
  const float* bq = (const float*)d_in[11];
  const float* Wk = (const float*)d_in[12];
  const float* bk = (const float*)d_in[13];
  const float* Wv = (const float*)d_in[14];
  const float* bv = (const float*)d_in[15];
  const float* dec_w_ih = (const float*)d_in[16];
  const float* dec_w_hh = (const float*)d_in[17];
  const float* dec_b_ih = (const float*)d_in[18];
  const float* dec_b_hh = (const float*)d_in[19];
  const float* fc_w = (const float*)d_in[20];
  const float* fc_b = (const float*)d_in[21];
  float* out = (float*)d_out;

  char* ws = (char*)d_ws;
  size_t off = 0;
  auto alloc = [&](size_t bytes){ void* p = ws + off; off += (bytes + 255) & ~(size_t)255; return p; };
  float* stateP   = (float*)alloc(512*48*4);
  float* qb       = (float*)alloc(512*48*4);
  float* m_part   = (float*)alloc(128*512*4);
  float* l_part   = (float*)alloc(128*512*4);
  float* acc_part = (float*)alloc(128*512*48*4);
  float* pred     = (float*)alloc(10240*48*4);
  float* pres     = (float*)alloc(10240*2*4);
  u16*   wihB     = (u16*)alloc(288*96*2);
  u16*   whhB     = (u16*)alloc(288*96*2);
  u16*   hb       = (u16*)alloc(10240*96*2);
  u16*   Kb       = (u16*)alloc(32768*64*2);
  u16*   Vc       = (u16*)alloc(128*48*256*2);

  wcvt_kernel<<<108, 256, 0, stream>>>(dec_w_ih, dec_w_hh, wihB, whhB);
  kv_kernel<<<1024, 256, 0, stream>>>(memory_past, memory_fut, Wk, bk, Wv, bv, Kb, Vc);
  enc_kernel<<<64, 256, 0, stream>>>(past, conv_w, conv_b, enc_w_ih, enc_w_hh,
                                     enc_b_ih, enc_b_hh, Wq, bq, stateP, qb);
  for (int it = 0; it < 20; ++it){
    flash_kernel<<<512, 256, 0, stream>>>(qb, Kb, Vc, m_part, l_part, acc_part);
    combine_kernel<<<512, 64, 0, stream>>>(m_part, l_part, acc_part, Wq, bq, qb, pred, it);
  }
  dec_kernel<true><<<640, 64, 0, stream>>>(wihB, dec_b_ih, dec_b_hh, stateP, pred, obs,
                                           hb, hb, pres, fc_w, fc_b, out, 0);
  for (int t = 1; t < 12; ++t)
    dec_kernel<false><<<640, 64, 0, stream>>>(whhB, dec_b_hh, dec_b_ih, stateP, pred, obs,
                                              hb, hb, pres, fc_w, fc_b, out, t);
}

// Round 2
// 975.031 us; speedup vs baseline: 1.1011x; 1.1011x over previous
//
#include <hip/hip_runtime.h>

typedef unsigned short u16;
typedef unsigned int u32;
typedef __attribute__((ext_vector_type(8))) short short8v;
typedef __attribute__((ext_vector_type(4))) float f32x4;

#define GLD_LDS(g, l) __builtin_amdgcn_global_load_lds( \
    (const __attribute__((address_space(1))) void*)(g), \
    (__attribute__((address_space(3))) void*)(l), 16, 0, 0)

__device__ __forceinline__ u16 f2bf(float f){
  union { float f; u32 u; } v; v.f = f;
  u32 r = v.u + 0x7FFFu + ((v.u >> 16) & 1u);
  return (u16)(r >> 16);
}
__device__ __forceinline__ float bf2f(u16 h){
  union { u32 u; float f; } v; v.u = ((u32)h) << 16;
  return v.f;
}
__device__ __forceinline__ u32 pk2(float a, float b){
  return (u32)f2bf(a) | ((u32)f2bf(b) << 16);
}
__device__ __forceinline__ float sigm(float x){ return 1.f/(1.f+__expf(-x)); }
__device__ __forceinline__ float tanh_fast(float x){ return 1.f - 2.f/(1.f+__expf(2.f*x)); }

// ---------------------------------------------------------------------------
// prep: convert all weight matrices to MFMA B-fragment layout, bf16, zero-padded.
// frag element order: (((nt*KC+kc)*4+qd)*16+ln)*8+j  <->  W[g=nt*16+ln][k=kc*32+qd*8+j]
__global__ void prep_kernel(const float* dih, const float* dhh,
    const float* eih, const float* ehh, const float* wq, const float* wk, const float* wv,
    u16* Dih, u16* Dhh, u16* Eih, u16* Ehh, u16* Qf, u16* Kf, u16* Vf)
{
  int idx = blockIdx.x*256 + threadIdx.x;
  const float* src; u16* dst; int KC, Kc, e;
  if      (idx < 27648){ src=dih; dst=Dih; KC=3; Kc=96; e=idx; }
  else if (idx < 55296){ src=dhh; dst=Dhh; KC=3; Kc=96; e=idx-27648; }
  else if (idx < 64512){ src=eih; dst=Eih; KC=2; Kc=48; e=idx-55296; }
  else if (idx < 73728){ src=ehh; dst=Ehh; KC=2; Kc=48; e=idx-64512; }
  else if (idx < 76800){ src=wq;  dst=Qf;  KC=2; Kc=48; e=idx-73728; }
  else if (idx < 79872){ src=wk;  dst=Kf;  KC=2; Kc=48; e=idx-76800; }
  else if (idx < 82944){ src=wv;  dst=Vf;  KC=2; Kc=48; e=idx-79872; }
  else return;
  int j = e & 7, ln = (e>>3) & 15, qd = (e>>7) & 3, tkc = e>>9;
  int kc = tkc % KC, nt = tkc / KC;
  int g = nt*16 + ln, k = kc*32 + qd*8 + j;
  dst[e] = (k < Kc) ? f2bf(src[g*Kc + k]) : (u16)0;
}

// ---------------------------------------------------------------------------
// kv: K = mp@Wk^T+bk -> Kb bf16 [32768][64] (plain, zero pad 48..63)
//     V = mf@Wv^T+bv -> Vc bf16 [128 ch][48][256] (transposed per-chunk, plain)
__global__ __launch_bounds__(256) void kv_kernel(
    const float* mp, const float* mf, const u16* wkB, const u16* wvB,
    const float* bk, const float* bv, u16* Kb, u16* Vc)
{
  __shared__ __align__(16) u16 sWk[3072], sWv[3072];
  __shared__ __align__(16) u16 sMp[4][16*72], sMf[4][16*72];
  int tid = threadIdx.x, wid = tid>>6, lane = tid&63, qd = lane>>4, ln = lane&15;
  int r0 = blockIdx.x*64 + wid*16;
  for (int i = wid; i < 6; i += 4) GLD_LDS((const char*)wkB + i*1024 + lane*16, (char*)sWk + i*1024);
  for (int i = wid; i < 6; i += 4) GLD_LDS((const char*)wvB + i*1024 + lane*16, (char*)sWv + i*1024);
  u16* smp = sMp[wid]; u16* smf = sMf[wid];
  for (int i = lane; i < 576; i += 64){ ((u32*)smp)[i] = 0; ((u32*)smf)[i] = 0; }
  for (int i = lane; i < 768; i += 64){
    int r = i/48, c = i%48;
    smp[r*72+c] = f2bf(mp[r0*48 + i]);
    smf[r*72+c] = f2bf(mf[r0*48 + i]);
  }
  __syncthreads();
  short8v aP[2], aF[2];
  #pragma unroll
  for (int kc = 0; kc < 2; ++kc){
    aP[kc] = *(const short8v*)&smp[ln*72 + kc*32 + qd*8];
    aF[kc] = *(const short8v*)&smf[ln*72 + kc*32 + qd*8];
  }
  f32x4 k3[3], v3[3];
  f32x4 zf = {0.f,0.f,0.f,0.f};
  #pragma unroll
  for (int nt = 0; nt < 3; ++nt){ k3[nt] = zf; v3[nt] = zf; }
  #pragma unroll
  for (int nt = 0; nt < 3; ++nt)
    #pragma unroll
    for (int kc = 0; kc < 2; ++kc){
      short8v fk = *(const short8v*)&sWk[((nt*2+kc)*4+qd)*128 + ln*8];
      short8v fv = *(const short8v*)&sWv[((nt*2+kc)*4+qd)*128 + ln*8];
      k3[nt] = __builtin_amdgcn_mfma_f32_16x16x32_bf16(aP[kc], fk, k3[nt], 0,0,0);
      v3[nt] = __builtin_amdgcn_mfma_f32_16x16x32_bf16(aF[kc], fv, v3[nt], 0,0,0);
    }
  #pragma unroll
  for (int nt = 0; nt < 3; ++nt)
    #pragma unroll
    for (int r = 0; r < 4; ++r){
      int key = r0 + qd*4 + r, d = nt*16 + ln;
      Kb[key*64 + d] = f2bf(k3[nt][r] + bk[d]);
      Vc[((key>>8)*48 + d)*256 + (key&255)] = f2bf(v3[nt][r] + bv[d]);
    }
  #pragma unroll
  for (int r = 0; r < 4; ++r)
    if (ln < 8){ int key = r0 + qd*4 + r; *(u32*)&Kb[key*64 + 48 + ln*2] = 0; }
}

// ---------------------------------------------------------------------------
// encoder: conv1d + 8-step GRU(48) via MFMA; one wave per 16 rows; grid 32.
__global__ __launch_bounds__(64) void enc_kernel(
    const float* past, const float* conv_w, const float* conv_b,
    const u16* encBih, const u16* encBhh, const u16* wqB,
    const float* b_ih, const float* b_hh, const float* bq,
    float* stateP, float* qf, u16* qbB)
{
  __shared__ __align__(16) u16 sWih[9216], sWhh[9216], sWq[3072];
  __shared__ __align__(16) u16 sEmb[16*72], sHb[16*72];
  __shared__ float sPast[256], sCw[288];
  int lane = threadIdx.x, qd = lane>>4, ln = lane&15;
  int r0 = blockIdx.x * 16;
  for (int i = 0; i < 18; ++i) GLD_LDS((const char*)encBih + i*1024 + lane*16, (char*)sWih + i*1024);
  for (int i = 0; i < 18; ++i) GLD_LDS((const char*)encBhh + i*1024 + lane*16, (char*)sWhh + i*1024);
  for (int i = 0; i < 6;  ++i) GLD_LDS((const char*)wqB    + i*1024 + lane*16, (char*)sWq  + i*1024);
  for (int i = lane; i < 256; i += 64) sPast[i] = past[r0*16 + i];
  for (int i = lane; i < 288; i += 64) sCw[i] = conv_w[i];
  for (int i = lane; i < 576; i += 64){ ((u32*)sEmb)[i] = 0; ((u32*)sHb)[i] = 0; }
  float biR[3],biZ[3],biN[3],bhR[3],bhZ[3],bhN[3];
  #pragma unroll
  for (int i = 0; i < 3; ++i){
    int d = i*16 + ln;
    biR[i]=b_ih[d]; biZ[i]=b_ih[48+d]; biN[i]=b_ih[96+d];
    bhR[i]=b_hh[d]; bhZ[i]=b_hh[48+d]; bhN[i]=b_hh[96+d];
  }
  float hreg[3][4];
  #pragma unroll
  for (int i = 0; i < 3; ++i) for (int r = 0; r < 4; ++r) hreg[i][r] = 0.f;
  __syncthreads();
  f32x4 zf = {0.f,0.f,0.f,0.f};
  for (int t = 0; t < 8; ++t){
    for (int i = lane; i < 768; i += 64){
      int r = i/48, d = i%48;
      float a = conv_b[d];
      #pragma unroll
      for (int kt = 0; kt < 3; ++kt){
        int tau = t + kt - 1;
        if (tau >= 0 && tau < 8){
          a += sPast[r*16 + tau*2 + 0] * sCw[d*6 + kt];
          a += sPast[r*16 + tau*2 + 1] * sCw[d*6 + 3 + kt];
        }
      }
      sEmb[r*72 + d] = f2bf(fmaxf(a, 0.f));
    }
    short8v aE[2], aH[2];
    #pragma unroll
    for (int kc = 0; kc < 2; ++kc){
      aE[kc] = *(const short8v*)&sEmb[ln*72 + kc*32 + qd*8];
      aH[kc] = *(const short8v*)&sHb [ln*72 + kc*32 + qd*8];
    }
    f32x4 gI[9], gH[9];
    #pragma unroll
    for (int nt = 0; nt < 9; ++nt){ gI[nt] = zf; gH[nt] = zf; }
    #pragma unroll
    for (int nt = 0; nt < 9; ++nt)
      #pragma unroll
      for (int kc = 0; kc < 2; ++kc){
        short8v fi = *(const short8v*)&sWih[((nt*2+kc)*4+qd)*128 + ln*8];
        short8v fh = *(const short8v*)&sWhh[((nt*2+kc)*4+qd)*128 + ln*8];
        gI[nt] = __builtin_amdgcn_mfma_f32_16x16x32_bf16(aE[kc], fi, gI[nt], 0,0,0);
        gH[nt] = __builtin_amdgcn_mfma_f32_16x16x32_bf16(aH[kc], fh, gH[nt], 0,0,0);
      }
    #pragma unroll
    for (int i3 = 0; i3 < 3; ++i3)
      #pragma unroll
      for (int r = 0; r < 4; ++r){
        float rr = sigm(gI[i3][r]+biR[i3] + gH[i3][r]+bhR[i3]);
        float zz = sigm(gI[i3+3][r]+biZ[i3] + gH[i3+3][r]+bhZ[i3]);
        float nn = tanh_fast(gI[i3+6][r]+biN[i3] + rr*(gH[i3+6][r]+bhN[i3]));
        float hv = (1.f-zz)*nn + zz*hreg[i3][r];
        hreg[i3][r] = hv;
        sHb[(qd*4+r)*72 + i3*16 + ln] = f2bf(hv);
      }
  }
  #pragma unroll
  for (int i3 = 0; i3 < 3; ++i3)
    #pragma unroll
    for (int r = 0; r < 4; ++r)
      stateP[(r0+qd*4+r)*48 + i3*16 + ln] = hreg[i3][r];
  // q0 = h @ Wq^T + bq
  short8v aH2[2];
  #pragma unroll
  for (int kc = 0; kc < 2; ++kc) aH2[kc] = *(const short8v*)&sHb[ln*72 + kc*32 + qd*8];
  f32x4 q3[3];
  #pragma unroll
  for (int nt = 0; nt < 3; ++nt){
    q3[nt] = zf;
    #pragma unroll
    for (int kc = 0; kc < 2; ++kc){
      short8v fq = *(const short8v*)&sWq[((nt*2+kc)*4+qd)*128 + ln*8];
      q3[nt] = __builtin_amdgcn_mfma_f32_16x16x32_bf16(aH2[kc], fq, q3[nt], 0,0,0);
    }
  }
  #pragma unroll
  for (int nt = 0; nt < 3; ++nt)
    #pragma unroll
    for (int r = 0; r < 4; ++r){
      int row = r0 + qd*4 + r, d = nt*16 + ln;
      float v = q3[nt][r] + bq[d];
      qf[row*48 + d] = v;
      qbB[row*64 + d] = f2bf(v);
    }
  #pragma unroll
  for (int r = 0; r < 4; ++r)
    if (ln < 8) *(u32*)&qbB[(r0+qd*4+r)*64 + 48 + ln*2] = 0;
}

// ---------------------------------------------------------------------------
// flash split-K attention: S^T = K·Q^T (softmax per-lane), O^T = V^T·P^T.
// grid 512 = 4 rowgroups x 128 chunks; 4 waves x 32 rows; barrier-free K-loop.
__global__ __launch_bounds__(256) void flash_kernel(
    const u16* qbB, const u16* Kb, const u16* Vc,
    float* m_part, float* l_part, float* acc_part)
{
  __shared__ __align__(16) u16 sP[4][2][16][72];
  int tid = threadIdx.x, wid = tid>>6, lane = tid&63;
  int qd = lane>>4, ln = lane&15;
  int bx = blockIdx.x, rg = bx>>7, ch = bx&127;
  int rowbase = rg*128 + wid*32;
  f32x4 zf = {0.f,0.f,0.f,0.f};
  short8v aq[2][2];
  #pragma unroll
  for (int rt = 0; rt < 2; ++rt)
    #pragma unroll
    for (int kc = 0; kc < 2; ++kc)
      aq[rt][kc] = *(const short8v*)(qbB + (rowbase + rt*16 + ln)*64 + kc*32 + qd*8);
  f32x4 acc[2][3];
  #pragma unroll
  for (int rt = 0; rt < 2; ++rt) for (int dt = 0; dt < 3; ++dt) acc[rt][dt] = zf;
  float mrun[2] = {-3.0e38f, -3.0e38f}, lrun[2] = {0.f, 0.f};

  for (int kt = 0; kt < 4; ++kt){
    const u16* kbase = Kb + (ch*256 + kt*64)*64;
    short8v kf[4][2];
    #pragma unroll
    for (int nt = 0; nt < 4; ++nt)
      #pragma unroll
      for (int kc = 0; kc < 2; ++kc)
        kf[nt][kc] = *(const short8v*)(kbase + (nt*16+ln)*64 + kc*32 + qd*8);
    short8v vf[2][3];
    #pragma unroll
    for (int kc = 0; kc < 2; ++kc)
      #pragma unroll
      for (int dt = 0; dt < 3; ++dt)
        vf[kc][dt] = *(const short8v*)(Vc + (ch*48 + dt*16 + ln)*256 + kt*64 + kc*32 + qd*8);
    #pragma unroll
    for (int rt = 0; rt < 2; ++rt){
      f32x4 s[4];
      #pragma unroll
      for (int nt = 0; nt < 4; ++nt){
        f32x4 z = zf;
        z = __builtin_amdgcn_mfma_f32_16x16x32_bf16(kf[nt][0], aq[rt][0], z, 0,0,0);
        z = __builtin_amdgcn_mfma_f32_16x16x32_bf16(kf[nt][1], aq[rt][1], z, 0,0,0);
        s[nt] = z;
      }
      float vmax = s[0][0];
      #pragma unroll
      for (int nt = 0; nt < 4; ++nt)
        #pragma unroll
        for (int r = 0; r < 4; ++r) vmax = fmaxf(vmax, s[nt][r]);
      vmax = fmaxf(vmax, __shfl_xor(vmax, 16));
      vmax = fmaxf(vmax, __shfl_xor(vmax, 32));
      float mnew = fmaxf(mrun[rt], vmax);
      float alpha = __expf(mrun[rt] - mnew);
      mrun[rt] = mnew;
      u16* sp = &sP[wid][rt][0][0];
      float lsum = 0.f;
      #pragma unroll
      for (int nt = 0; nt < 4; ++nt){
        float p0 = __expf(s[nt][0]-mnew), p1 = __expf(s[nt][1]-mnew);
        float p2 = __expf(s[nt][2]-mnew), p3 = __expf(s[nt][3]-mnew);
        lsum += (p0+p1)+(p2+p3);
        uint2 pk; pk.x = pk2(p0,p1); pk.y = pk2(p2,p3);
        *(uint2*)&sp[ln*72 + nt*16 + qd*4] = pk;
      }
      lsum += __shfl_xor(lsum, 16);
      lsum += __shfl_xor(lsum, 32);
      lrun[rt] = lrun[rt]*alpha + lsum;
      #pragma unroll
      for (int dt = 0; dt < 3; ++dt){
        acc[rt][dt][0] *= alpha; acc[rt][dt][1] *= alpha;
        acc[rt][dt][2] *= alpha; acc[rt][dt][3] *= alpha;
      }
    }
    #pragma unroll
    for (int rt = 0; rt < 2; ++rt){
      const u16* sp = &sP[wid][rt][0][0];
      short8v pb0 = *(const short8v*)&sp[ln*72 + qd*8];
      short8v pb1 = *(const short8v*)&sp[ln*72 + 32 + qd*8];
      #pragma unroll
      for (int dt = 0; dt < 3; ++dt){
        acc[rt][dt] = __builtin_amdgcn_mfma_f32_16x16x32_bf16(vf[0][dt], pb0, acc[rt][dt], 0,0,0);
        acc[rt][dt] = __builtin_amdgcn_mfma_f32_16x16x32_bf16(vf[1][dt], pb1, acc[rt][dt], 0,0,0);
      }
    }
  }
  #pragma unroll
  for (int rt = 0; rt < 2; ++rt){
    int row = rowbase + rt*16 + ln;
    if (lane < 16){
      m_part[row*128 + ch] = mrun[rt];
      l_part[row*128 + ch] = lrun[rt];
    }
    #pragma unroll
    for (int dt = 0; dt < 3; ++dt)
      *(f32x4*)(acc_part + (size_t)(row*128 + ch)*48 + dt*16 + qd*4) = acc[rt][dt];
  }
}

// ---------------------------------------------------------------------------
// combine: partials -> att; pred; c = q+att; q_next = c@Wq^T+bq (fp32 + bf16)
__global__ __launch_bounds__(256) void combine_kernel(
    const float* m_part, const float* l_part, const float* acc_part,
    const float* Wq, const float* bq, float* qf, u16* qbB, float* pred, int iter)
{
  __shared__ float sEw[128], sL[128], sAtt[4][48], sC[48];
  int row = blockIdx.x, tid = threadIdx.x;
  int qq = tid>>6, d = tid&63;
  if (tid < 128){ sEw[tid] = m_part[row*128 + tid]; sL[tid] = l_part[row*128 + tid]; }
  __syncthreads();
  float mg = -3.0e38f;
  #pragma unroll 8
  for (int c = 0; c < 128; ++c) mg = fmaxf(mg, sEw[c]);
  __syncthreads();
  if (tid < 128) sEw[tid] = __expf(sEw[tid] - mg);
  __syncthreads();
  float lg = 0.f;
  #pragma unroll 8
  for (int c = 0; c < 128; ++c) lg += sEw[c]*sL[c];
  if (d < 48){
    float att = 0.f;
    #pragma unroll 8
    for (int c = qq*32; c < qq*32 + 32; ++c)
      att += sEw[c]*acc_part[(size_t)(row*128 + c)*48 + d];
    sAtt[qq][d] = att;
  }
  __syncthreads();
  if (qq == 0 && d < 48){
    float a = (sAtt[0][d]+sAtt[1][d]+sAtt[2][d]+sAtt[3][d]) / lg;
    pred[(row*20 + iter)*48 + d] = a;
    sC[d] = qf[row*48 + d] + a;
  }
  __syncthreads();
  if (qq == 0){
    if (d < 48){
      float a = bq[d];
      #pragma unroll
      for (int k = 0; k < 48; ++k) a += sC[k]*Wq[d*48 + k];
      qf[row*48 + d] = a;
      qbB[row*64 + d] = f2bf(a);
    } else {
      qbB[row*64 + d] = 0;
    }
  }
}

// ---------------------------------------------------------------------------
// decoder GRU(96) step via MFMA; 4 waves x 16 rows; weights staged in LDS.
template<bool STEP0>
__global__ __launch_bounds__(256) void dec_kernel(
    const u16* wB, const float* b_own, const float* b_oth,
    const float* stateP, const float* pred, const float* obs,
    const u16* h_in, u16* h_out, float* pres,
    const float* fc_w, const float* fc_b, float* out, int t)
{
  __shared__ __align__(16) u16 sW[27648];
  __shared__ __align__(16) u16 sX[4][16*104];
  int tid = threadIdx.x, wid = tid>>6, lane = tid&63, qd = lane>>4, ln = lane&15;
  int r0 = blockIdx.x*64, rw = r0 + wid*16;
  for (int i = wid; i < 54; i += 4) GLD_LDS((const char*)wB + i*1024 + lane*16, (char*)sW + i*1024);
  u16* sx = sX[wid];
  if (STEP0){
    for (int i = lane; i < 1536; i += 64){
      int r = i/96, k = i%96, row = rw + r;
      float v = (k < 48) ? stateP[(row/20)*48 + k] : pred[row*48 + (k-48)];
      sx[r*104 + k] = f2bf(v);
    }
  } else {
    const u32* src = (const u32*)(h_in + rw*96);
    for (int i = lane; i < 768; i += 64){
      int r = i/48, c = i%48;
      ((u32*)sx)[r*52 + c] = src[i];
    }
  }
  __syncthreads();
  short8v xa[3];
  #pragma unroll
  for (int kc = 0; kc < 3; ++kc) xa[kc] = *(const short8v*)&sx[ln*104 + kc*32 + qd*8];
  f32x4 acc[18];
  f32x4 zf = {0.f,0.f,0.f,0.f};
  #pragma unroll
  for (int i = 0; i < 18; ++i) acc[i] = zf;
  #pragma unroll
  for (int nt = 0; nt < 18; ++nt)
    #pragma unroll
    for (int kc = 0; kc < 3; ++kc){
      short8v wb = *(const short8v*)&sW[((nt*3+kc)*4+qd)*128 + ln*8];
      acc[nt] = __builtin_amdgcn_mfma_f32_16x16x32_bf16(xa[kc], wb, acc[nt], 0,0,0);
    }
  float px[4] = {0,0,0,0}, py[4] = {0,0,0,0};
  #pragma unroll
  for (int r = 0; r < 4; ++r){
    int row = rw + qd*4 + r;
    #pragma unroll
    for (int i = 0; i < 6; ++i){
      int d = i*16 + ln;
      float g1r = acc[i][r]    + b_own[d];
      float g1z = acc[i+6][r]  + b_own[96+d];
      float g1n = acc[i+12][r] + b_own[192+d];
      float rr = sigm(g1r + b_oth[d]);
      float zz = sigm(g1z + b_oth[96+d]);
      float inn, hn;
      if (STEP0){ inn = g1n; hn = b_oth[192+d]; }
      else      { inn = b_oth[192+d]; hn = g1n; }
      float nn = tanh_fast(inn + rr*hn);
      float hold = STEP0 ? 0.f : bf2f(sx[(qd*4+r)*104 + d]);
      float hv = (1.f-zz)*nn + zz*hold;
      h_out[row*96 + d] = f2bf(hv);
      px[r] += fc_w[d]*hv;
      py[r] += fc_w[96+d]*hv;
    }
  }
  #pragma unroll
  for (int msk = 8; msk >= 1; msk >>= 1)
    #pragma unroll
    for (int r = 0; r < 4; ++r){
      px[r] += __shfl_xor(px[r], msk);
      py[r] += __shfl_xor(py[r], msk);
    }
  if (ln == 0){
    #pragma unroll
    for (int r = 0; r < 4; ++r){
      int row = rw + qd*4 + r;
      float p0, p1;
      if (STEP0){ p0 = obs[(row/20)*16+14]; p1 = obs[(row/20)*16+15]; }
      else      { p0 = pres[row*2]; p1 = pres[row*2+1]; }
      p0 += px[r] + fc_b[0];
      p1 += py[r] + fc_b[1];
      pres[row*2] = p0; pres[row*2+1] = p1;
      out[(row*12+t)*2+0] = p0;
      out[(row*12+t)*2+1] = p1;
    }
  }
}

// ---------------------------------------------------------------------------
extern "C" void kernel_launch(void* const* d_in, const int* in_sizes, int n_in,
                              void* d_out, int out_size, void* d_ws, size_t ws_size,
                              hipStream_t stream)
{
  const float* past        = (const float*)d_in[0];
  const float* obs         = (const float*)d_in[1];
  const float* conv_w      = (const float*)d_in[2];
  const float* conv_b      = (const float*)d_in[3];
  const float* enc_w_ih    = (const float*)d_in[4];
  const float* enc_w_hh    = (const float*)d_in[5];
  const float* enc_b_ih    = (const float*)d_in[6];
  const float* enc_b_hh    = (const float*)d_in[7];
  const float* memory_past = (const float*)d_in[8];
  const float* memory_fut  = (const float*)d_in[9];
  const float* Wq = (const float*)d_in[10];
  const float* bq = (const float*)d_in[11];
  const float* Wk = (const float*)d_in[12];
  const float* bk = (const float*)d_in[13];
  const float* Wv = (const float*)d_in[14];
  const float* bv = (const float*)d_in[15];
  const float* dec_w_ih = (const float*)d_in[16];
  const float* dec_w_hh = (const float*)d_in[17];
  const float* dec_b_ih = (const float*)d_in[18];
  const float* dec_b_hh = (const float*)d_in[19];
  const float* fc_w = (const float*)d_in[20];
  const float* fc_b = (const float*)d_in[21];
  float* out = (float*)d_out;

  char* ws = (char*)d_ws;
  size_t off = 0;
  auto alloc = [&](size_t bytes){ void* p = ws + off; off += (bytes + 255) & ~(size_t)255; return p; };
  float* stateP   = (float*)alloc(512*48*4);
  float* qf       = (float*)alloc(512*48*4);
  u16*   qbB      = (u16*)alloc(512*64*2);
  float* m_part   = (float*)alloc(512*128*4);
  float* l_part   = (float*)alloc(512*128*4);
  float* acc_part = (float*)alloc((size_t)512*128*48*4);
  float* pred     = (float*)alloc(10240*48*4);
  float* pres     = (float*)alloc(10240*2*4);
  u16*   hb       = (u16*)alloc(10240*96*2);
  u16*   Kb       = (u16*)alloc((size_t)32768*64*2);
  u16*   Vc       = (u16*)alloc((size_t)128*48*256*2);
  u16*   Dih      = (u16*)alloc(27648*2);
  u16*   Dhh      = (u16*)alloc(27648*2);
  u16*   Eih      = (u16*)alloc(9216*2);
  u16*   Ehh      = (u16*)alloc(9216*2);
  u16*   Qfrag    = (u16*)alloc(3072*2);
  u16*   Kfrag    = (u16*)alloc(3072*2);
  u16*   Vfrag    = (u16*)alloc(3072*2);

  prep_kernel<<<324, 256, 0, stream>>>(dec_w_ih, dec_w_hh, enc_w_ih, enc_w_hh, Wq, Wk, Wv,
                                       Dih, Dhh, Eih, Ehh, Qfrag, Kfrag, Vfrag);
  kv_kernel<<<512, 256, 0, stream>>>(memory_past, memory_fut, Kfrag, Vfrag, bk, bv, Kb, Vc);
  enc_kernel<<<32, 64, 0, stream>>>(past, conv_w, conv_b, Eih, Ehh, Qfrag,
                                    enc_b_ih, enc_b_hh, bq, stateP, qf, qbB);
  for (int it = 0; it < 20; ++it){
    flash_kernel<<<512, 256, 0, stream>>>(qbB, Kb, Vc, m_part, l_part, acc_part);
    combine_kernel<<<512, 256, 0, stream>>>(m_part, l_part, acc_part, Wq, bq, qf, qbB, pred, it);
  }
  dec_kernel<true><<<160, 256, 0, stream>>>(Dih, dec_b_ih, dec_b_hh, stateP, pred, obs,
                                            hb, hb, pres, fc_w, fc_b, out, 0);
  for (int t = 1; t < 12; ++t)
    dec_kernel<false><<<160, 256, 0, stream>>>(Dhh, dec_b_hh, dec_b_ih, stateP, pred, obs,
                                               hb, hb, pres, fc_w, fc_b, out, t);
}